// Round 8
// baseline (242.470 us; speedup 1.0000x reference)
//
#include <hip/hip_runtime.h>
#include <hip/hip_fp16.h>
#include <math.h>

#define NO 50000
#define NR 2000
#define NE 600000
#define D  128
#define NEG_SLOPE 0.2f
#define CAP 448    // per-rider edges cached in LDS (mean 300, max ~370)
#define SLOT 512   // fixed capacity per rider segment
#define NB2 64     // LDS-hist scatter blocks (first NB2 blocks of prep_scan)
#define CH2 ((NE + NB2 - 1) / NB2)   // 9375 edges per scatter chunk
#define NREG 10    // register-stashed pass-2 iterations (covers edge idx < 320)

// ---------------------------------------------------------------------------
// K1: zero per-rider counters (block 0)  ||  precompute_wv (block 1)
__global__ void prep_init(int* __restrict__ cnt,
                          const float* __restrict__ Ws1, const float* __restrict__ as1,
                          const float* __restrict__ Wd1, const float* __restrict__ ad1,
                          const float* __restrict__ Ws2, const float* __restrict__ as2,
                          const float* __restrict__ Wd2, const float* __restrict__ ad2,
                          float* __restrict__ wsv1, float* __restrict__ wdv1,
                          float* __restrict__ wsv2, float* __restrict__ wdv2) {
    int t = threadIdx.x;
    if (blockIdx.x == 0) {
        for (int i = t; i < NR; i += 256) cnt[i] = 0;
    } else if (t < 128) {
        int k = t;
        float s1 = 0.f, d1 = 0.f, s2 = 0.f, d2 = 0.f;
        for (int j = 0; j < D; ++j) {
            s1 += Ws1[k * D + j] * as1[j];
            d1 += Wd1[k * D + j] * ad1[j];
            s2 += Ws2[k * D + j] * as2[j];
            d2 += Wd2[k * D + j] * ad2[j];
        }
        wsv1[k] = s1; wdv1[k] = d1; wsv2[k] = s2; wdv2[k] = d2;
    }
}

// ---------------------------------------------------------------------------
// K2: blocks 0..NB2-1 = LDS-hist counting scatter; blocks NB2.. = node prep.
__global__ void prep_scan(const float* __restrict__ x, const float* __restrict__ xr,
                          const float* __restrict__ wsv1, const float* __restrict__ wsv2,
                          const float* __restrict__ wdv1,
                          float* __restrict__ as1o, float* __restrict__ as2o,
                          float* __restrict__ ad1r, __half* __restrict__ x16,
                          const int* __restrict__ oi, const int* __restrict__ ri,
                          int* __restrict__ cnt, int2* __restrict__ sOE) {
    int b = blockIdx.x;
    if (b < NB2) {
        __shared__ int h[NR];    // chunk histogram, then write cursor
        __shared__ int bs[NR];   // per-rider base within global segment
        int t = threadIdx.x;
        int lo = b * CH2;
        int hi = lo + CH2; if (hi > NE) hi = NE;
        for (int i = t; i < NR; i += 256) h[i] = 0;
        __syncthreads();
        for (int e = lo + t; e < hi; e += 256) atomicAdd(&h[ri[e]], 1);
        __syncthreads();
        for (int i = t; i < NR; i += 256) {
            int c = h[i];
            if (c) bs[i] = atomicAdd(&cnt[i], c);
            h[i] = 0;
        }
        __syncthreads();
        for (int e = lo + t; e < hi; e += 256) {
            int r = ri[e];
            int rank = atomicAdd(&h[r], 1);
            sOE[(size_t)r * SLOT + bs[r] + rank] = make_int2(oi[e], e);
        }
        return;
    }
    int lane = threadIdx.x & 63;
    int nb = b - NB2;
    if (nb < NO / 4) {
        int row = nb * 4 + (threadIdx.x >> 6);
        float2 xv = ((const float2*)(x + (size_t)row * D))[lane];
        float2 w1 = ((const float2*)wsv1)[lane];
        float2 w2 = ((const float2*)wsv2)[lane];
        float rx0 = fmaxf(xv.x, 0.f), rx1 = fmaxf(xv.y, 0.f);
        ((__half2*)(x16 + (size_t)row * D))[lane] = __floats2half2_rn(xv.x, xv.y);
        float a1 = xv.x * w1.x + xv.y * w1.y;
        float a2 = rx0 * w2.x + rx1 * w2.y;
        for (int off = 32; off; off >>= 1) {
            a1 += __shfl_down(a1, off);
            a2 += __shfl_down(a2, off);
        }
        if (lane == 0) { as1o[row] = a1; as2o[row] = a2; }
    } else {
        int row = (nb - NO / 4) * 4 + (threadIdx.x >> 6);
        if (row >= NR) return;
        float2 xv = ((const float2*)(xr + (size_t)row * D))[lane];
        float2 w1 = ((const float2*)wdv1)[lane];
        float a = xv.x * w1.x + xv.y * w1.y;
        for (int off = 32; off; off >>= 1) a += __shfl_down(a, off);
        if (lane == 0) ad1r[row] = a;
    }
}

// ---------------------------------------------------------------------------
// K3: fused layer-1 + layer-2 + scoring.  NEW: pass 2 stashes its row slices
// in statically-indexed register arrays (NREG unrolled iterations); pass 3
// scores from registers — one full gather pass eliminated, no LDS/barrier
// cost, no occupancy change (160 VGPR -> 3 waves/SIMD >= observed 2).
__global__ void __launch_bounds__(256)
agg12(const __half* __restrict__ x16,
      const float* __restrict__ as1o, const float* __restrict__ as2o,
      const float* __restrict__ ad1r,
      const int* __restrict__ cnt, const int2* __restrict__ sOE,
      const float* __restrict__ W1, const float* __restrict__ b1,
      const float* __restrict__ wdv2,
      const float* __restrict__ W2, const float* __restrict__ b2,
      float* __restrict__ out) {
    __shared__ int   sO[CAP];
    __shared__ int   sE[CAP];
    __shared__ float red[256];
    __shared__ float red8[256][9];   // +1 pad breaks stride-8 bank conflicts
    __shared__ float tl[D];
    __shared__ float r2s[D];
    __shared__ float wred[4];
    int r = blockIdx.x, t = threadIdx.x;
    int base = r * SLOT, n = cnt[r];
    int grp = t >> 4, lh = t & 15;

    int lim = n < CAP ? n : CAP;
    for (int i = t; i < lim; i += 256) {
        int2 v = sOE[base + i];
        sO[i] = v.x; sE[i] = v.y;
    }
    float ad1 = ad1r[r];
    __syncthreads();

    // ================= Layer 1: fused softmax + gather =================
    float acc[8];
#pragma unroll
    for (int k = 0; k < 8; ++k) acc[k] = 0.f;
    float ls = 0.f;
    if (n <= CAP) {
        int i = grp;
        for (; i + 16 < n; i += 32) {
            int o0 = sO[i], o1 = sO[i + 16];
            uint4 h0 = ((const uint4*)(x16 + (size_t)o0 * D))[lh];
            uint4 h1 = ((const uint4*)(x16 + (size_t)o1 * D))[lh];
            float e0 = as1o[o0] + ad1;
            float e1 = as1o[o1] + ad1;
            e0 = (e0 > 0.f) ? e0 : NEG_SLOPE * e0;
            e1 = (e1 > 0.f) ? e1 : NEG_SLOPE * e1;
            float a0 = __expf(e0), a1 = __expf(e1);
            ls += a0 + a1;
            const __half2* p0 = (const __half2*)&h0;
            const __half2* p1 = (const __half2*)&h1;
#pragma unroll
            for (int q = 0; q < 4; ++q) {
                float2 f0 = __half22float2(p0[q]);
                float2 f1 = __half22float2(p1[q]);
                acc[2 * q]     += a0 * f0.x + a1 * f1.x;
                acc[2 * q + 1] += a0 * f0.y + a1 * f1.y;
            }
        }
        if (i < n) {
            int o0 = sO[i];
            uint4 h0 = ((const uint4*)(x16 + (size_t)o0 * D))[lh];
            float e0 = as1o[o0] + ad1;
            e0 = (e0 > 0.f) ? e0 : NEG_SLOPE * e0;
            float a0 = __expf(e0);
            ls += a0;
            const __half2* p0 = (const __half2*)&h0;
#pragma unroll
            for (int q = 0; q < 4; ++q) {
                float2 f0 = __half22float2(p0[q]);
                acc[2 * q]     += a0 * f0.x;
                acc[2 * q + 1] += a0 * f0.y;
            }
        }
    } else {
        for (int i = grp; i < n; i += 16) {
            int o0 = (i < CAP) ? sO[i] : sOE[base + i].x;
            uint4 h0 = ((const uint4*)(x16 + (size_t)o0 * D))[lh];
            float e0 = as1o[o0] + ad1;
            e0 = (e0 > 0.f) ? e0 : NEG_SLOPE * e0;
            float a0 = __expf(e0);
            ls += a0;
            const __half2* p0 = (const __half2*)&h0;
#pragma unroll
            for (int q = 0; q < 4; ++q) {
                float2 f0 = __half22float2(p0[q]);
                acc[2 * q]     += a0 * f0.x;
                acc[2 * q + 1] += a0 * f0.y;
            }
        }
    }
    {   // ls identical across the 16 lanes of a group; keep lane lh==0 only
        float lsv = (lh == 0) ? ls : 0.f;
        lsv += __shfl_down(lsv, 32);
        lsv += __shfl_down(lsv, 16);
        lsv += __shfl_down(lsv, 8);
        lsv += __shfl_down(lsv, 4);
        lsv += __shfl_down(lsv, 2);
        lsv += __shfl_down(lsv, 1);
        if ((t & 63) == 0) wred[t >> 6] = lsv;
#pragma unroll
        for (int k = 0; k < 8; ++k) red8[t][k] = acc[k];
    }
    __syncthreads();
    if (t < D) {
        int lh2 = t >> 3, k = t & 7;
        float s = 0.f;
#pragma unroll
        for (int g = 0; g < 16; ++g) s += red8[g * 16 + lh2][k];
        float inv1 = 1.f / (wred[0] + wred[1] + wred[2] + wred[3] + 1e-16f);
        tl[t] = s * inv1;
    }
    __syncthreads();

    // GEMM1 -> ad2 (scalar, stays on-chip)
    {
        int d = t & 127, h = t >> 7;
        float a = 0.f;
        for (int k = h * 64; k < h * 64 + 64; ++k) a += tl[k] * W1[k * D + d];
        red[t] = a;
    }
    __syncthreads();
    {
        float v = 0.f;
        if (t < 128) v = fmaxf(red[t] + red[t + 128] + b1[t], 0.f) * wdv2[t];
        v += __shfl_down(v, 32);
        v += __shfl_down(v, 16);
        v += __shfl_down(v, 8);
        v += __shfl_down(v, 4);
        v += __shfl_down(v, 2);
        v += __shfl_down(v, 1);
        if ((t & 63) == 0) wred[t >> 6] = v;
    }
    __syncthreads();
    float ad2 = wred[0] + wred[1] + wred[2] + wred[3];
    __syncthreads();   // guard: wred is rewritten at end of pass 2

    // ============ Layer 2: fused softmax + gather, rows stashed in regs ====
    uint4 sva[NREG], svb[NREG];      // statically-indexed (full unroll) only
#pragma unroll
    for (int k = 0; k < 8; ++k) acc[k] = 0.f;
    ls = 0.f;
    if (n <= CAP) {
#pragma unroll
        for (int it = 0; it < NREG; ++it) {
            int i = grp + it * 32;
            if (i < n) {
                int o0 = sO[i];
                uint4 h0 = ((const uint4*)(x16 + (size_t)o0 * D))[lh];
                sva[it] = h0;
                float e0 = as2o[o0] + ad2;
                e0 = (e0 > 0.f) ? e0 : NEG_SLOPE * e0;
                float a0 = __expf(e0);
                ls += a0;
                const __half2* p0 = (const __half2*)&h0;
#pragma unroll
                for (int q = 0; q < 4; ++q) {
                    float2 f0 = __half22float2(p0[q]);
                    acc[2 * q]     += a0 * fmaxf(f0.x, 0.f);
                    acc[2 * q + 1] += a0 * fmaxf(f0.y, 0.f);
                }
            }
            if (i + 16 < n) {
                int o1 = sO[i + 16];
                uint4 h1 = ((const uint4*)(x16 + (size_t)o1 * D))[lh];
                svb[it] = h1;
                float e1 = as2o[o1] + ad2;
                e1 = (e1 > 0.f) ? e1 : NEG_SLOPE * e1;
                float a1 = __expf(e1);
                ls += a1;
                const __half2* p1 = (const __half2*)&h1;
#pragma unroll
                for (int q = 0; q < 4; ++q) {
                    float2 f1 = __half22float2(p1[q]);
                    acc[2 * q]     += a1 * fmaxf(f1.x, 0.f);
                    acc[2 * q + 1] += a1 * fmaxf(f1.y, 0.f);
                }
            }
        }
        for (int i = grp + NREG * 32; i < n; i += 16) {   // tail (rare)
            int o0 = sO[i];
            uint4 h0 = ((const uint4*)(x16 + (size_t)o0 * D))[lh];
            float e0 = as2o[o0] + ad2;
            e0 = (e0 > 0.f) ? e0 : NEG_SLOPE * e0;
            float a0 = __expf(e0);
            ls += a0;
            const __half2* p0 = (const __half2*)&h0;
#pragma unroll
            for (int q = 0; q < 4; ++q) {
                float2 f0 = __half22float2(p0[q]);
                acc[2 * q]     += a0 * fmaxf(f0.x, 0.f);
                acc[2 * q + 1] += a0 * fmaxf(f0.y, 0.f);
            }
        }
    } else {
        for (int i = grp; i < n; i += 16) {
            int o0 = (i < CAP) ? sO[i] : sOE[base + i].x;
            uint4 h0 = ((const uint4*)(x16 + (size_t)o0 * D))[lh];
            float e0 = as2o[o0] + ad2;
            e0 = (e0 > 0.f) ? e0 : NEG_SLOPE * e0;
            float a0 = __expf(e0);
            ls += a0;
            const __half2* p0 = (const __half2*)&h0;
#pragma unroll
            for (int q = 0; q < 4; ++q) {
                float2 f0 = __half22float2(p0[q]);
                acc[2 * q]     += a0 * fmaxf(f0.x, 0.f);
                acc[2 * q + 1] += a0 * fmaxf(f0.y, 0.f);
            }
        }
    }
    {
        float lsv = (lh == 0) ? ls : 0.f;
        lsv += __shfl_down(lsv, 32);
        lsv += __shfl_down(lsv, 16);
        lsv += __shfl_down(lsv, 8);
        lsv += __shfl_down(lsv, 4);
        lsv += __shfl_down(lsv, 2);
        lsv += __shfl_down(lsv, 1);
        if ((t & 63) == 0) wred[t >> 6] = lsv;
#pragma unroll
        for (int k = 0; k < 8; ++k) red8[t][k] = acc[k];
    }
    __syncthreads();
    if (t < D) {
        int lh2 = t >> 3, k = t & 7;
        float s = 0.f;
#pragma unroll
        for (int g = 0; g < 16; ++g) s += red8[g * 16 + lh2][k];
        float inv2 = 1.f / (wred[0] + wred[1] + wred[2] + wred[3] + 1e-16f);
        tl[t] = s * inv2;
    }
    __syncthreads();

    // GEMM2 -> r2 (fp32, stays in LDS)
    {
        int d = t & 127, h = t >> 7;
        float a = 0.f;
        for (int k = h * 64; k < h * 64 + 64; ++k) a += tl[k] * W2[k * D + d];
        red[t] = a;
    }
    __syncthreads();
    if (t < 128) r2s[t] = red[t] + red[t + 128] + b2[t];
    __syncthreads();

    // ============ Scoring: dot(relu(x[o]), r2) from the register stash =====
    float r2v[8];
#pragma unroll
    for (int k = 0; k < 8; ++k) r2v[k] = r2s[lh * 8 + k];
    if (n <= CAP) {
#pragma unroll
        for (int it = 0; it < NREG; ++it) {
            int i = grp + it * 32;
            if (i < n) {
                uint4 h0 = sva[it];
                int e0 = sE[i];
                const __half2* p0 = (const __half2*)&h0;
                float pa = 0.f;
#pragma unroll
                for (int q = 0; q < 4; ++q) {
                    float2 f0 = __half22float2(p0[q]);
                    pa += fmaxf(f0.x, 0.f) * r2v[2 * q] + fmaxf(f0.y, 0.f) * r2v[2 * q + 1];
                }
                pa += __shfl_xor(pa, 8);
                pa += __shfl_xor(pa, 4);
                pa += __shfl_xor(pa, 2);
                pa += __shfl_xor(pa, 1);
                if (lh == 0) out[e0] = 1.f / (1.f + __expf(-pa));
            }
            if (i + 16 < n) {
                uint4 h1 = svb[it];
                int e1 = sE[i + 16];
                const __half2* p1 = (const __half2*)&h1;
                float pb = 0.f;
#pragma unroll
                for (int q = 0; q < 4; ++q) {
                    float2 f1 = __half22float2(p1[q]);
                    pb += fmaxf(f1.x, 0.f) * r2v[2 * q] + fmaxf(f1.y, 0.f) * r2v[2 * q + 1];
                }
                pb += __shfl_xor(pb, 8);
                pb += __shfl_xor(pb, 4);
                pb += __shfl_xor(pb, 2);
                pb += __shfl_xor(pb, 1);
                if (lh == 0) out[e1] = 1.f / (1.f + __expf(-pb));
            }
        }
        for (int i = grp + NREG * 32; i < n; i += 16) {   // tail (rare)
            int o0 = sO[i], e0 = sE[i];
            uint4 h0 = ((const uint4*)(x16 + (size_t)o0 * D))[lh];
            const __half2* p0 = (const __half2*)&h0;
            float pa = 0.f;
#pragma unroll
            for (int q = 0; q < 4; ++q) {
                float2 f0 = __half22float2(p0[q]);
                pa += fmaxf(f0.x, 0.f) * r2v[2 * q] + fmaxf(f0.y, 0.f) * r2v[2 * q + 1];
            }
            pa += __shfl_xor(pa, 8);
            pa += __shfl_xor(pa, 4);
            pa += __shfl_xor(pa, 2);
            pa += __shfl_xor(pa, 1);
            if (lh == 0) out[e0] = 1.f / (1.f + __expf(-pa));
        }
    } else {
        for (int i = grp; i < n; i += 16) {
            int o0, e0;
            if (i < CAP) { o0 = sO[i]; e0 = sE[i]; }
            else { int2 v = sOE[base + i]; o0 = v.x; e0 = v.y; }
            uint4 h0 = ((const uint4*)(x16 + (size_t)o0 * D))[lh];
            const __half2* p0 = (const __half2*)&h0;
            float pa = 0.f;
#pragma unroll
            for (int q = 0; q < 4; ++q) {
                float2 f0 = __half22float2(p0[q]);
                pa += fmaxf(f0.x, 0.f) * r2v[2 * q] + fmaxf(f0.y, 0.f) * r2v[2 * q + 1];
            }
            pa += __shfl_xor(pa, 8);
            pa += __shfl_xor(pa, 4);
            pa += __shfl_xor(pa, 2);
            pa += __shfl_xor(pa, 1);
            if (lh == 0) out[e0] = 1.f / (1.f + __expf(-pa));
        }
    }
}

// ---------------------------------------------------------------------------
extern "C" void kernel_launch(void* const* d_in, const int* in_sizes, int n_in,
                              void* d_out, int out_size, void* d_ws, size_t ws_size,
                              hipStream_t stream) {
    const float* x_order = (const float*)d_in[0];
    const float* x_rider = (const float*)d_in[1];
    const int*   oi      = (const int*)d_in[2];
    const int*   ri      = (const int*)d_in[3];
    const float* Ws1 = (const float*)d_in[4];
    const float* Wd1 = (const float*)d_in[5];
    const float* as1 = (const float*)d_in[6];
    const float* ad1 = (const float*)d_in[7];
    const float* b1  = (const float*)d_in[8];
    const float* Ws2 = (const float*)d_in[9];
    const float* Wd2 = (const float*)d_in[10];
    const float* as2 = (const float*)d_in[11];
    const float* ad2 = (const float*)d_in[12];
    const float* b2  = (const float*)d_in[13];
    float* out = (float*)d_out;

    // workspace carve-up (16B-aligned chunks)
    char* w = (char*)d_ws;
    float* wsv1 = (float*)w; w += 512;
    float* wdv1 = (float*)w; w += 512;
    float* wsv2 = (float*)w; w += 512;
    float* wdv2 = (float*)w; w += 512;
    float* as1o = (float*)w; w += (size_t)NO * 4;        // 200 KB
    float* as2o = (float*)w; w += (size_t)NO * 4;
    float* ad1r = (float*)w; w += (size_t)NR * 4;        // 8 KB
    int* cnt    = (int*)w;   w += (size_t)NR * 4;
    int2* sOE   = (int2*)w;  w += (size_t)NR * SLOT * 8; // 8 MB
    __half* x16 = (__half*)w; w += (size_t)NO * D * 2;   // 12.8 MB

    prep_init<<<2, 256, 0, stream>>>(cnt,
                                     Ws1, as1, Wd1, ad1, Ws2, as2, Wd2, ad2,
                                     wsv1, wdv1, wsv2, wdv2);
    prep_scan<<<NB2 + NO / 4 + NR / 4, 256, 0, stream>>>(x_order, x_rider,
                                                         wsv1, wsv2, wdv1,
                                                         as1o, as2o, ad1r, x16,
                                                         oi, ri, cnt, sOE);
    agg12<<<NR, 256, 0, stream>>>(x16, as1o, as2o, ad1r, cnt, sOE,
                                  Ws1, b1, wdv2, Ws2, b2, out);
}

// Round 9
// 207.701 us; speedup vs baseline: 1.1674x; 1.1674x over previous
//
#include <hip/hip_runtime.h>
#include <hip/hip_fp16.h>
#include <math.h>

#define NO 50000
#define NR 2000
#define NE 600000
#define D  128
#define NEG_SLOPE 0.2f
#define CAP 448    // per-rider edges cached in LDS (mean 300, max ~370)
#define SLOT 512   // fixed capacity per rider segment
#define NB2 128    // LDS-hist scatter blocks (first NB2 blocks of prep_scan)
#define CH2 ((NE + NB2 - 1) / NB2)   // 4688 edges per scatter chunk

// ---------------------------------------------------------------------------
// K1: zero per-rider counters (block 0)  ||  precompute_wv (block 1)
__global__ void prep_init(int* __restrict__ cnt,
                          const float* __restrict__ Ws1, const float* __restrict__ as1,
                          const float* __restrict__ Wd1, const float* __restrict__ ad1,
                          const float* __restrict__ Ws2, const float* __restrict__ as2,
                          const float* __restrict__ Wd2, const float* __restrict__ ad2,
                          float* __restrict__ wsv1, float* __restrict__ wdv1,
                          float* __restrict__ wsv2, float* __restrict__ wdv2) {
    int t = threadIdx.x;
    if (blockIdx.x == 0) {
        for (int i = t; i < NR; i += 256) cnt[i] = 0;
    } else if (t < 128) {
        int k = t;
        float s1 = 0.f, d1 = 0.f, s2 = 0.f, d2 = 0.f;
        for (int j = 0; j < D; ++j) {
            s1 += Ws1[k * D + j] * as1[j];
            d1 += Wd1[k * D + j] * ad1[j];
            s2 += Ws2[k * D + j] * as2[j];
            d2 += Wd2[k * D + j] * ad2[j];
        }
        wsv1[k] = s1; wdv1[k] = d1; wsv2[k] = s2; wdv2[k] = d2;
    }
}

// ---------------------------------------------------------------------------
// K2: blocks 0..NB2-1 = LDS-hist counting scatter; blocks NB2.. = node prep.
__global__ void prep_scan(const float* __restrict__ x, const float* __restrict__ xr,
                          const float* __restrict__ wsv1, const float* __restrict__ wsv2,
                          const float* __restrict__ wdv1,
                          float* __restrict__ as1o, float* __restrict__ as2o,
                          float* __restrict__ ad1r, __half* __restrict__ x16,
                          const int* __restrict__ oi, const int* __restrict__ ri,
                          int* __restrict__ cnt, int2* __restrict__ sOE) {
    int b = blockIdx.x;
    if (b < NB2) {
        __shared__ int h[NR];    // chunk histogram, then write cursor
        __shared__ int bs[NR];   // per-rider base within global segment
        int t = threadIdx.x;
        int lo = b * CH2;
        int hi = lo + CH2; if (hi > NE) hi = NE;
        for (int i = t; i < NR; i += 256) h[i] = 0;
        __syncthreads();
        for (int e = lo + t; e < hi; e += 256) atomicAdd(&h[ri[e]], 1);
        __syncthreads();
        for (int i = t; i < NR; i += 256) {
            int c = h[i];
            if (c) bs[i] = atomicAdd(&cnt[i], c);
            h[i] = 0;
        }
        __syncthreads();
        for (int e = lo + t; e < hi; e += 256) {
            int r = ri[e];
            int rank = atomicAdd(&h[r], 1);
            sOE[(size_t)r * SLOT + bs[r] + rank] = make_int2(oi[e], e);
        }
        return;
    }
    int lane = threadIdx.x & 63;
    int nb = b - NB2;
    if (nb < NO / 4) {
        int row = nb * 4 + (threadIdx.x >> 6);
        float2 xv = ((const float2*)(x + (size_t)row * D))[lane];
        float2 w1 = ((const float2*)wsv1)[lane];
        float2 w2 = ((const float2*)wsv2)[lane];
        float rx0 = fmaxf(xv.x, 0.f), rx1 = fmaxf(xv.y, 0.f);
        ((__half2*)(x16 + (size_t)row * D))[lane] = __floats2half2_rn(xv.x, xv.y);
        float a1 = xv.x * w1.x + xv.y * w1.y;
        float a2 = rx0 * w2.x + rx1 * w2.y;
        for (int off = 32; off; off >>= 1) {
            a1 += __shfl_down(a1, off);
            a2 += __shfl_down(a2, off);
        }
        if (lane == 0) { as1o[row] = a1; as2o[row] = a2; }
    } else {
        int row = (nb - NO / 4) * 4 + (threadIdx.x >> 6);
        if (row >= NR) return;
        float2 xv = ((const float2*)(xr + (size_t)row * D))[lane];
        float2 w1 = ((const float2*)wdv1)[lane];
        float a = xv.x * w1.x + xv.y * w1.y;
        for (int off = 32; off; off >>= 1) a += __shfl_down(a, off);
        if (lane == 0) ad1r[row] = a;
    }
}

// ---------------------------------------------------------------------------
// K3: fused layer-1 + layer-2 + scoring (R1/R7 structure — best measured).
//  NEW: 4-row unrolled gathers (4 loads in flight per 16-lane group) in all
//  three passes — doubles memory-level parallelism, transient registers only.
__global__ void __launch_bounds__(256)
agg12(const __half* __restrict__ x16,
      const float* __restrict__ as1o, const float* __restrict__ as2o,
      const float* __restrict__ ad1r,
      const int* __restrict__ cnt, const int2* __restrict__ sOE,
      const float* __restrict__ W1, const float* __restrict__ b1,
      const float* __restrict__ wdv2,
      const float* __restrict__ W2, const float* __restrict__ b2,
      float* __restrict__ out) {
    __shared__ int   sO[CAP];
    __shared__ int   sE[CAP];
    __shared__ float red[256];
    __shared__ float red8[256][9];   // +1 pad breaks stride-8 bank conflicts
    __shared__ float tl[D];
    __shared__ float r2s[D];
    __shared__ float wred[4];
    int r = blockIdx.x, t = threadIdx.x;
    int base = r * SLOT, n = cnt[r];
    int grp = t >> 4, lh = t & 15;

    int lim = n < CAP ? n : CAP;
    for (int i = t; i < lim; i += 256) {
        int2 v = sOE[base + i];
        sO[i] = v.x; sE[i] = v.y;
    }
    float ad1 = ad1r[r];
    __syncthreads();

    // ================= Layer 1: fused softmax + gather (4-deep) ============
    float acc[8];
#pragma unroll
    for (int k = 0; k < 8; ++k) acc[k] = 0.f;
    float ls = 0.f;
    if (n <= CAP) {
        int i = grp;
        for (; i + 48 < n; i += 64) {
            int o0 = sO[i], o1 = sO[i + 16], o2 = sO[i + 32], o3 = sO[i + 48];
            uint4 h0 = ((const uint4*)(x16 + (size_t)o0 * D))[lh];
            uint4 h1 = ((const uint4*)(x16 + (size_t)o1 * D))[lh];
            uint4 h2 = ((const uint4*)(x16 + (size_t)o2 * D))[lh];
            uint4 h3 = ((const uint4*)(x16 + (size_t)o3 * D))[lh];
            float e0 = as1o[o0] + ad1, e1 = as1o[o1] + ad1;
            float e2 = as1o[o2] + ad1, e3 = as1o[o3] + ad1;
            e0 = (e0 > 0.f) ? e0 : NEG_SLOPE * e0;
            e1 = (e1 > 0.f) ? e1 : NEG_SLOPE * e1;
            e2 = (e2 > 0.f) ? e2 : NEG_SLOPE * e2;
            e3 = (e3 > 0.f) ? e3 : NEG_SLOPE * e3;
            float a0 = __expf(e0), a1 = __expf(e1);
            float a2 = __expf(e2), a3 = __expf(e3);
            ls += (a0 + a1) + (a2 + a3);
            const __half2* p0 = (const __half2*)&h0;
            const __half2* p1 = (const __half2*)&h1;
            const __half2* p2 = (const __half2*)&h2;
            const __half2* p3 = (const __half2*)&h3;
#pragma unroll
            for (int q = 0; q < 4; ++q) {
                float2 f0 = __half22float2(p0[q]);
                float2 f1 = __half22float2(p1[q]);
                float2 f2 = __half22float2(p2[q]);
                float2 f3 = __half22float2(p3[q]);
                acc[2 * q]     += (a0 * f0.x + a1 * f1.x) + (a2 * f2.x + a3 * f3.x);
                acc[2 * q + 1] += (a0 * f0.y + a1 * f1.y) + (a2 * f2.y + a3 * f3.y);
            }
        }
        for (; i + 16 < n; i += 32) {
            int o0 = sO[i], o1 = sO[i + 16];
            uint4 h0 = ((const uint4*)(x16 + (size_t)o0 * D))[lh];
            uint4 h1 = ((const uint4*)(x16 + (size_t)o1 * D))[lh];
            float e0 = as1o[o0] + ad1;
            float e1 = as1o[o1] + ad1;
            e0 = (e0 > 0.f) ? e0 : NEG_SLOPE * e0;
            e1 = (e1 > 0.f) ? e1 : NEG_SLOPE * e1;
            float a0 = __expf(e0), a1 = __expf(e1);
            ls += a0 + a1;
            const __half2* p0 = (const __half2*)&h0;
            const __half2* p1 = (const __half2*)&h1;
#pragma unroll
            for (int q = 0; q < 4; ++q) {
                float2 f0 = __half22float2(p0[q]);
                float2 f1 = __half22float2(p1[q]);
                acc[2 * q]     += a0 * f0.x + a1 * f1.x;
                acc[2 * q + 1] += a0 * f0.y + a1 * f1.y;
            }
        }
        if (i < n) {
            int o0 = sO[i];
            uint4 h0 = ((const uint4*)(x16 + (size_t)o0 * D))[lh];
            float e0 = as1o[o0] + ad1;
            e0 = (e0 > 0.f) ? e0 : NEG_SLOPE * e0;
            float a0 = __expf(e0);
            ls += a0;
            const __half2* p0 = (const __half2*)&h0;
#pragma unroll
            for (int q = 0; q < 4; ++q) {
                float2 f0 = __half22float2(p0[q]);
                acc[2 * q]     += a0 * f0.x;
                acc[2 * q + 1] += a0 * f0.y;
            }
        }
    } else {
        for (int i = grp; i < n; i += 16) {
            int o0 = (i < CAP) ? sO[i] : sOE[base + i].x;
            uint4 h0 = ((const uint4*)(x16 + (size_t)o0 * D))[lh];
            float e0 = as1o[o0] + ad1;
            e0 = (e0 > 0.f) ? e0 : NEG_SLOPE * e0;
            float a0 = __expf(e0);
            ls += a0;
            const __half2* p0 = (const __half2*)&h0;
#pragma unroll
            for (int q = 0; q < 4; ++q) {
                float2 f0 = __half22float2(p0[q]);
                acc[2 * q]     += a0 * f0.x;
                acc[2 * q + 1] += a0 * f0.y;
            }
        }
    }
    {   // ls identical across the 16 lanes of a group; keep lane lh==0 only
        float lsv = (lh == 0) ? ls : 0.f;
        lsv += __shfl_down(lsv, 32);
        lsv += __shfl_down(lsv, 16);
        lsv += __shfl_down(lsv, 8);
        lsv += __shfl_down(lsv, 4);
        lsv += __shfl_down(lsv, 2);
        lsv += __shfl_down(lsv, 1);
        if ((t & 63) == 0) wred[t >> 6] = lsv;
#pragma unroll
        for (int k = 0; k < 8; ++k) red8[t][k] = acc[k];
    }
    __syncthreads();
    if (t < D) {
        int lh2 = t >> 3, k = t & 7;
        float s = 0.f;
#pragma unroll
        for (int g = 0; g < 16; ++g) s += red8[g * 16 + lh2][k];
        float inv1 = 1.f / (wred[0] + wred[1] + wred[2] + wred[3] + 1e-16f);
        tl[t] = s * inv1;
    }
    __syncthreads();

    // GEMM1 -> ad2 (scalar, stays on-chip)
    {
        int d = t & 127, h = t >> 7;
        float a = 0.f;
        for (int k = h * 64; k < h * 64 + 64; ++k) a += tl[k] * W1[k * D + d];
        red[t] = a;
    }
    __syncthreads();
    {
        float v = 0.f;
        if (t < 128) v = fmaxf(red[t] + red[t + 128] + b1[t], 0.f) * wdv2[t];
        v += __shfl_down(v, 32);
        v += __shfl_down(v, 16);
        v += __shfl_down(v, 8);
        v += __shfl_down(v, 4);
        v += __shfl_down(v, 2);
        v += __shfl_down(v, 1);
        if ((t & 63) == 0) wred[t >> 6] = v;
    }
    __syncthreads();
    float ad2 = wred[0] + wred[1] + wred[2] + wred[3];
    __syncthreads();   // guard: wred is rewritten at end of pass 2

    // ================= Layer 2: fused softmax + gather (4-deep) ============
#pragma unroll
    for (int k = 0; k < 8; ++k) acc[k] = 0.f;
    ls = 0.f;
    if (n <= CAP) {
        int i = grp;
        for (; i + 48 < n; i += 64) {
            int o0 = sO[i], o1 = sO[i + 16], o2 = sO[i + 32], o3 = sO[i + 48];
            uint4 h0 = ((const uint4*)(x16 + (size_t)o0 * D))[lh];
            uint4 h1 = ((const uint4*)(x16 + (size_t)o1 * D))[lh];
            uint4 h2 = ((const uint4*)(x16 + (size_t)o2 * D))[lh];
            uint4 h3 = ((const uint4*)(x16 + (size_t)o3 * D))[lh];
            float e0 = as2o[o0] + ad2, e1 = as2o[o1] + ad2;
            float e2 = as2o[o2] + ad2, e3 = as2o[o3] + ad2;
            e0 = (e0 > 0.f) ? e0 : NEG_SLOPE * e0;
            e1 = (e1 > 0.f) ? e1 : NEG_SLOPE * e1;
            e2 = (e2 > 0.f) ? e2 : NEG_SLOPE * e2;
            e3 = (e3 > 0.f) ? e3 : NEG_SLOPE * e3;
            float a0 = __expf(e0), a1 = __expf(e1);
            float a2 = __expf(e2), a3 = __expf(e3);
            ls += (a0 + a1) + (a2 + a3);
            const __half2* p0 = (const __half2*)&h0;
            const __half2* p1 = (const __half2*)&h1;
            const __half2* p2 = (const __half2*)&h2;
            const __half2* p3 = (const __half2*)&h3;
#pragma unroll
            for (int q = 0; q < 4; ++q) {
                float2 f0 = __half22float2(p0[q]);
                float2 f1 = __half22float2(p1[q]);
                float2 f2 = __half22float2(p2[q]);
                float2 f3 = __half22float2(p3[q]);
                acc[2 * q]     += (a0 * fmaxf(f0.x, 0.f) + a1 * fmaxf(f1.x, 0.f))
                                + (a2 * fmaxf(f2.x, 0.f) + a3 * fmaxf(f3.x, 0.f));
                acc[2 * q + 1] += (a0 * fmaxf(f0.y, 0.f) + a1 * fmaxf(f1.y, 0.f))
                                + (a2 * fmaxf(f2.y, 0.f) + a3 * fmaxf(f3.y, 0.f));
            }
        }
        for (; i + 16 < n; i += 32) {
            int o0 = sO[i], o1 = sO[i + 16];
            uint4 h0 = ((const uint4*)(x16 + (size_t)o0 * D))[lh];
            uint4 h1 = ((const uint4*)(x16 + (size_t)o1 * D))[lh];
            float e0 = as2o[o0] + ad2;
            float e1 = as2o[o1] + ad2;
            e0 = (e0 > 0.f) ? e0 : NEG_SLOPE * e0;
            e1 = (e1 > 0.f) ? e1 : NEG_SLOPE * e1;
            float a0 = __expf(e0), a1 = __expf(e1);
            ls += a0 + a1;
            const __half2* p0 = (const __half2*)&h0;
            const __half2* p1 = (const __half2*)&h1;
#pragma unroll
            for (int q = 0; q < 4; ++q) {
                float2 f0 = __half22float2(p0[q]);
                float2 f1 = __half22float2(p1[q]);
                acc[2 * q]     += a0 * fmaxf(f0.x, 0.f) + a1 * fmaxf(f1.x, 0.f);
                acc[2 * q + 1] += a0 * fmaxf(f0.y, 0.f) + a1 * fmaxf(f1.y, 0.f);
            }
        }
        if (i < n) {
            int o0 = sO[i];
            uint4 h0 = ((const uint4*)(x16 + (size_t)o0 * D))[lh];
            float e0 = as2o[o0] + ad2;
            e0 = (e0 > 0.f) ? e0 : NEG_SLOPE * e0;
            float a0 = __expf(e0);
            ls += a0;
            const __half2* p0 = (const __half2*)&h0;
#pragma unroll
            for (int q = 0; q < 4; ++q) {
                float2 f0 = __half22float2(p0[q]);
                acc[2 * q]     += a0 * fmaxf(f0.x, 0.f);
                acc[2 * q + 1] += a0 * fmaxf(f0.y, 0.f);
            }
        }
    } else {
        for (int i = grp; i < n; i += 16) {
            int o0 = (i < CAP) ? sO[i] : sOE[base + i].x;
            uint4 h0 = ((const uint4*)(x16 + (size_t)o0 * D))[lh];
            float e0 = as2o[o0] + ad2;
            e0 = (e0 > 0.f) ? e0 : NEG_SLOPE * e0;
            float a0 = __expf(e0);
            ls += a0;
            const __half2* p0 = (const __half2*)&h0;
#pragma unroll
            for (int q = 0; q < 4; ++q) {
                float2 f0 = __half22float2(p0[q]);
                acc[2 * q]     += a0 * fmaxf(f0.x, 0.f);
                acc[2 * q + 1] += a0 * fmaxf(f0.y, 0.f);
            }
        }
    }
    {
        float lsv = (lh == 0) ? ls : 0.f;
        lsv += __shfl_down(lsv, 32);
        lsv += __shfl_down(lsv, 16);
        lsv += __shfl_down(lsv, 8);
        lsv += __shfl_down(lsv, 4);
        lsv += __shfl_down(lsv, 2);
        lsv += __shfl_down(lsv, 1);
        if ((t & 63) == 0) wred[t >> 6] = lsv;
#pragma unroll
        for (int k = 0; k < 8; ++k) red8[t][k] = acc[k];
    }
    __syncthreads();
    if (t < D) {
        int lh2 = t >> 3, k = t & 7;
        float s = 0.f;
#pragma unroll
        for (int g = 0; g < 16; ++g) s += red8[g * 16 + lh2][k];
        float inv2 = 1.f / (wred[0] + wred[1] + wred[2] + wred[3] + 1e-16f);
        tl[t] = s * inv2;
    }
    __syncthreads();

    // GEMM2 -> r2 (fp32, stays in LDS)
    {
        int d = t & 127, h = t >> 7;
        float a = 0.f;
        for (int k = h * 64; k < h * 64 + 64; ++k) a += tl[k] * W2[k * D + d];
        red[t] = a;
    }
    __syncthreads();
    if (t < 128) r2s[t] = red[t] + red[t + 128] + b2[t];
    __syncthreads();

    // ================= Scoring: dot(relu(x[o]), r2) per edge (4-deep) ======
    float r2v[8];
#pragma unroll
    for (int k = 0; k < 8; ++k) r2v[k] = r2s[lh * 8 + k];
    if (n <= CAP) {
        int i = grp;
        for (; i + 48 < n; i += 64) {
            int o0 = sO[i], o1 = sO[i + 16], o2 = sO[i + 32], o3 = sO[i + 48];
            int e0 = sE[i], e1 = sE[i + 16], e2 = sE[i + 32], e3 = sE[i + 48];
            uint4 h0 = ((const uint4*)(x16 + (size_t)o0 * D))[lh];
            uint4 h1 = ((const uint4*)(x16 + (size_t)o1 * D))[lh];
            uint4 h2 = ((const uint4*)(x16 + (size_t)o2 * D))[lh];
            uint4 h3 = ((const uint4*)(x16 + (size_t)o3 * D))[lh];
            const __half2* p0 = (const __half2*)&h0;
            const __half2* p1 = (const __half2*)&h1;
            const __half2* p2 = (const __half2*)&h2;
            const __half2* p3 = (const __half2*)&h3;
            float pa = 0.f, pb = 0.f, pc = 0.f, pd = 0.f;
#pragma unroll
            for (int q = 0; q < 4; ++q) {
                float2 f0 = __half22float2(p0[q]);
                float2 f1 = __half22float2(p1[q]);
                float2 f2 = __half22float2(p2[q]);
                float2 f3 = __half22float2(p3[q]);
                pa += fmaxf(f0.x, 0.f) * r2v[2 * q] + fmaxf(f0.y, 0.f) * r2v[2 * q + 1];
                pb += fmaxf(f1.x, 0.f) * r2v[2 * q] + fmaxf(f1.y, 0.f) * r2v[2 * q + 1];
                pc += fmaxf(f2.x, 0.f) * r2v[2 * q] + fmaxf(f2.y, 0.f) * r2v[2 * q + 1];
                pd += fmaxf(f3.x, 0.f) * r2v[2 * q] + fmaxf(f3.y, 0.f) * r2v[2 * q + 1];
            }
            pa += __shfl_xor(pa, 8); pb += __shfl_xor(pb, 8);
            pc += __shfl_xor(pc, 8); pd += __shfl_xor(pd, 8);
            pa += __shfl_xor(pa, 4); pb += __shfl_xor(pb, 4);
            pc += __shfl_xor(pc, 4); pd += __shfl_xor(pd, 4);
            pa += __shfl_xor(pa, 2); pb += __shfl_xor(pb, 2);
            pc += __shfl_xor(pc, 2); pd += __shfl_xor(pd, 2);
            pa += __shfl_xor(pa, 1); pb += __shfl_xor(pb, 1);
            pc += __shfl_xor(pc, 1); pd += __shfl_xor(pd, 1);
            if (lh == 0) {
                out[e0] = 1.f / (1.f + __expf(-pa));
                out[e1] = 1.f / (1.f + __expf(-pb));
                out[e2] = 1.f / (1.f + __expf(-pc));
                out[e3] = 1.f / (1.f + __expf(-pd));
            }
        }
        for (; i + 16 < n; i += 32) {
            int o0 = sO[i], o1 = sO[i + 16];
            int e0 = sE[i], e1 = sE[i + 16];
            uint4 h0 = ((const uint4*)(x16 + (size_t)o0 * D))[lh];
            uint4 h1 = ((const uint4*)(x16 + (size_t)o1 * D))[lh];
            const __half2* p0 = (const __half2*)&h0;
            const __half2* p1 = (const __half2*)&h1;
            float pa = 0.f, pb = 0.f;
#pragma unroll
            for (int q = 0; q < 4; ++q) {
                float2 f0 = __half22float2(p0[q]);
                float2 f1 = __half22float2(p1[q]);
                pa += fmaxf(f0.x, 0.f) * r2v[2 * q] + fmaxf(f0.y, 0.f) * r2v[2 * q + 1];
                pb += fmaxf(f1.x, 0.f) * r2v[2 * q] + fmaxf(f1.y, 0.f) * r2v[2 * q + 1];
            }
            pa += __shfl_xor(pa, 8); pb += __shfl_xor(pb, 8);
            pa += __shfl_xor(pa, 4); pb += __shfl_xor(pb, 4);
            pa += __shfl_xor(pa, 2); pb += __shfl_xor(pb, 2);
            pa += __shfl_xor(pa, 1); pb += __shfl_xor(pb, 1);
            if (lh == 0) {
                out[e0] = 1.f / (1.f + __expf(-pa));
                out[e1] = 1.f / (1.f + __expf(-pb));
            }
        }
        if (i < n) {
            int o0 = sO[i], e0 = sE[i];
            uint4 h0 = ((const uint4*)(x16 + (size_t)o0 * D))[lh];
            const __half2* p0 = (const __half2*)&h0;
            float pa = 0.f;
#pragma unroll
            for (int q = 0; q < 4; ++q) {
                float2 f0 = __half22float2(p0[q]);
                pa += fmaxf(f0.x, 0.f) * r2v[2 * q] + fmaxf(f0.y, 0.f) * r2v[2 * q + 1];
            }
            pa += __shfl_xor(pa, 8);
            pa += __shfl_xor(pa, 4);
            pa += __shfl_xor(pa, 2);
            pa += __shfl_xor(pa, 1);
            if (lh == 0) out[e0] = 1.f / (1.f + __expf(-pa));
        }
    } else {
        for (int i = grp; i < n; i += 16) {
            int o0, e0;
            if (i < CAP) { o0 = sO[i]; e0 = sE[i]; }
            else { int2 v = sOE[base + i]; o0 = v.x; e0 = v.y; }
            uint4 h0 = ((const uint4*)(x16 + (size_t)o0 * D))[lh];
            const __half2* p0 = (const __half2*)&h0;
            float pa = 0.f;
#pragma unroll
            for (int q = 0; q < 4; ++q) {
                float2 f0 = __half22float2(p0[q]);
                pa += fmaxf(f0.x, 0.f) * r2v[2 * q] + fmaxf(f0.y, 0.f) * r2v[2 * q + 1];
            }
            pa += __shfl_xor(pa, 8);
            pa += __shfl_xor(pa, 4);
            pa += __shfl_xor(pa, 2);
            pa += __shfl_xor(pa, 1);
            if (lh == 0) out[e0] = 1.f / (1.f + __expf(-pa));
        }
    }
}

// ---------------------------------------------------------------------------
extern "C" void kernel_launch(void* const* d_in, const int* in_sizes, int n_in,
                              void* d_out, int out_size, void* d_ws, size_t ws_size,
                              hipStream_t stream) {
    const float* x_order = (const float*)d_in[0];
    const float* x_rider = (const float*)d_in[1];
    const int*   oi      = (const int*)d_in[2];
    const int*   ri      = (const int*)d_in[3];
    const float* Ws1 = (const float*)d_in[4];
    const float* Wd1 = (const float*)d_in[5];
    const float* as1 = (const float*)d_in[6];
    const float* ad1 = (const float*)d_in[7];
    const float* b1  = (const float*)d_in[8];
    const float* Ws2 = (const float*)d_in[9];
    const float* Wd2 = (const float*)d_in[10];
    const float* as2 = (const float*)d_in[11];
    const float* ad2 = (const float*)d_in[12];
    const float* b2  = (const float*)d_in[13];
    float* out = (float*)d_out;

    // workspace carve-up (16B-aligned chunks)
    char* w = (char*)d_ws;
    float* wsv1 = (float*)w; w += 512;
    float* wdv1 = (float*)w; w += 512;
    float* wsv2 = (float*)w; w += 512;
    float* wdv2 = (float*)w; w += 512;
    float* as1o = (float*)w; w += (size_t)NO * 4;        // 200 KB
    float* as2o = (float*)w; w += (size_t)NO * 4;
    float* ad1r = (float*)w; w += (size_t)NR * 4;        // 8 KB
    int* cnt    = (int*)w;   w += (size_t)NR * 4;
    int2* sOE   = (int2*)w;  w += (size_t)NR * SLOT * 8; // 8 MB
    __half* x16 = (__half*)w; w += (size_t)NO * D * 2;   // 12.8 MB

    prep_init<<<2, 256, 0, stream>>>(cnt,
                                     Ws1, as1, Wd1, ad1, Ws2, as2, Wd2, ad2,
                                     wsv1, wdv1, wsv2, wdv2);
    prep_scan<<<NB2 + NO / 4 + NR / 4, 256, 0, stream>>>(x_order, x_rider,
                                                         wsv1, wsv2, wdv1,
                                                         as1o, as2o, ad1r, x16,
                                                         oi, ri, cnt, sOE);
    agg12<<<NR, 256, 0, stream>>>(x16, as1o, as2o, ad1r, cnt, sOE,
                                  Ws1, b1, wdv2, Ws2, b2, out);
}